// Round 6
// baseline (318.713 us; speedup 1.0000x reference)
//
#include <hip/hip_runtime.h>

#define N_NODES 100000
#define F_IN    128
#define H_DIM   64
#define C_DIM   16
#define NBKT    391            // ceil(100000 / 256) buckets of 256 nodes (dst>>8)
#define BKT_PAD 16             // one bucket counter per 64B line (atomic line-serialization)
#define CHUNK   4096           // edges per block in bucket phases

__device__ __forceinline__ void fma4(float4& acc, float s, const float4& w) {
    acc.x = fmaf(s, w.x, acc.x);
    acc.y = fmaf(s, w.y, acc.y);
    acc.z = fmaf(s, w.z, acc.z);
    acc.w = fmaf(s, w.w, acc.w);
}
__device__ __forceinline__ void add4(float4& a, const float4& v) {
    a.x += v.x; a.y += v.y; a.z += v.z; a.w += v.w;
}

// ---------- CSR build: two-level bucketed counting sort ----------
__global__ void k_zero_b(int* __restrict__ b) {
    int i = blockIdx.x * blockDim.x + threadIdx.x;
    if (i < NBKT * BKT_PAD) b[i] = 0;
}

__global__ __launch_bounds__(256) void k_bhist(const int2* __restrict__ edges,
                                               int* __restrict__ bkt_tot, int E) {
    __shared__ int cnt[NBKT];
    for (int t = threadIdx.x; t < NBKT; t += 256) cnt[t] = 0;
    __syncthreads();
    int base = blockIdx.x * CHUNK;
    #pragma unroll
    for (int i = 0; i < CHUNK / 256; ++i) {
        int e = base + i * 256 + threadIdx.x;
        if (e < E) atomicAdd(&cnt[edges[e].y >> 8], 1);
    }
    __syncthreads();
    for (int t = threadIdx.x; t < NBKT; t += 256)
        if (cnt[t]) atomicAdd(&bkt_tot[t * BKT_PAD], cnt[t]);
}

__global__ __launch_bounds__(512) void k_bscan(const int* __restrict__ bkt_tot,
                                               int* __restrict__ bkt_base,
                                               int* __restrict__ bkt_tail) {
    __shared__ int s[512];
    int t = threadIdx.x;
    int v = (t < NBKT) ? bkt_tot[t * BKT_PAD] : 0;
    s[t] = v;
    __syncthreads();
    #pragma unroll
    for (int off = 1; off < 512; off <<= 1) {
        int u = (t >= off) ? s[t - off] : 0;
        __syncthreads();
        s[t] += u;
        __syncthreads();
    }
    if (t < NBKT) {
        int b = s[t] - v;                   // exclusive scan
        bkt_base[t] = b;
        bkt_tail[t * BKT_PAD] = b;
    }
}

__global__ __launch_bounds__(256) void k_bfill(const int2* __restrict__ edges,
                                               int* __restrict__ bkt_tail,
                                               int2* __restrict__ pairs, int E) {
    __shared__ int cnt[NBKT];
    __shared__ int row[NBKT];
    for (int t = threadIdx.x; t < NBKT; t += 256) cnt[t] = 0;
    __syncthreads();
    int base = blockIdx.x * CHUNK;
    int2 ed[CHUNK / 256];                   // 16 int2 in registers (static idx via unroll)
    #pragma unroll
    for (int i = 0; i < CHUNK / 256; ++i) {
        int e = base + i * 256 + threadIdx.x;
        if (e < E) { ed[i] = edges[e]; atomicAdd(&cnt[ed[i].y >> 8], 1); }
    }
    __syncthreads();
    for (int t = threadIdx.x; t < NBKT; t += 256)
        row[t] = cnt[t] ? atomicAdd(&bkt_tail[t * BKT_PAD], cnt[t]) : 0;
    __syncthreads();
    #pragma unroll
    for (int i = 0; i < CHUNK / 256; ++i) {
        int e = base + i * 256 + threadIdx.x;
        if (e < E) {
            int r = atomicAdd(&row[ed[i].y >> 8], 1);   // LDS atomic
            pairs[r] = ed[i];
        }
    }
}

// one block per bucket: node-ordered base/cnt/dinv + dense CSR scatter (L2-hot region)
__global__ __launch_bounds__(256) void k_bnode(const int2* __restrict__ pairs,
                                               const int* __restrict__ bkt_base,
                                               int* __restrict__ csr_src,
                                               int* __restrict__ node_base,
                                               int* __restrict__ node_cnt,
                                               float* __restrict__ dinv, int E) {
    __shared__ int cnt[256];
    __shared__ int s[256];
    __shared__ int row[256];
    int b = blockIdx.x;
    int t = threadIdx.x;
    cnt[t] = 0;
    __syncthreads();
    int start = bkt_base[b];
    int end   = (b + 1 < NBKT) ? bkt_base[b + 1] : E;
    for (int e = start + t; e < end; e += 256)
        atomicAdd(&cnt[pairs[e].y & 255], 1);
    __syncthreads();
    int c = cnt[t];
    s[t] = c;
    __syncthreads();
    #pragma unroll
    for (int off = 1; off < 256; off <<= 1) {
        int u = (t >= off) ? s[t - off] : 0;
        __syncthreads();
        s[t] += u;
        __syncthreads();
    }
    int gbase = start + s[t] - c;
    row[t] = gbase;
    int node = b * 256 + t;
    if (node < N_NODES) {
        node_base[node] = gbase;
        node_cnt[node]  = c;
        dinv[node]      = rsqrtf((float)(c + 1));   // deg = cnt + 1 (self loop)
    }
    __syncthreads();
    for (int e = start + t; e < end; e += 256) {
        int2 p = pairs[e];
        int pos = atomicAdd(&row[p.y & 255], 1);    // LDS atomic
        csr_src[pos] = p.x;
    }
}

// ---------- GEMM1: g1[N,64] = dinv[row] * (x[N,128] @ W1[128,64]) ----------
__global__ __launch_bounds__(256) void k_gemm1(const float* __restrict__ x,
                                               const float* __restrict__ W1,
                                               const float* __restrict__ dinv,
                                               float* __restrict__ g1) {
    __shared__ float4 wlds[F_IN * 16];               // 32 KB
    int tid = threadIdx.x;
    const float4* w4 = (const float4*)W1;
    #pragma unroll
    for (int i = 0; i < 8; ++i) wlds[tid + 256 * i] = w4[tid + 256 * i];
    __syncthreads();

    int row  = blockIdx.x * 16 + (tid >> 4);         // N = 6250*16 exactly
    int colq = tid & 15;
    const float4* x4 = (const float4*)(x + (size_t)row * F_IN);
    float4 acc = {0.f, 0.f, 0.f, 0.f};
    #pragma unroll
    for (int k4 = 0; k4 < F_IN / 4; ++k4) {
        float4 xv = x4[k4];
        fma4(acc, xv.x, wlds[(4 * k4 + 0) * 16 + colq]);
        fma4(acc, xv.y, wlds[(4 * k4 + 1) * 16 + colq]);
        fma4(acc, xv.z, wlds[(4 * k4 + 2) * 16 + colq]);
        fma4(acc, xv.w, wlds[(4 * k4 + 3) * 16 + colq]);
    }
    float di = dinv[row];
    acc.x *= di; acc.y *= di; acc.z *= di; acc.w *= di;
    ((float4*)(g1 + (size_t)row * H_DIM))[colq] = acc;
}

// ---------- gather layer 1: 16-lane group per node (4 nodes/wave), float4 ----------
// agg1[i] = b1 + dinv[i] * ( g1[i] + sum_{src} g1[src] )
__global__ __launch_bounds__(256) void k_gather1(const int* __restrict__ csr_src,
                                                 const int* __restrict__ base,
                                                 const int* __restrict__ cnt,
                                                 const float* __restrict__ dinv,
                                                 const float4* __restrict__ g1,   // [N][16]
                                                 const float* __restrict__ b1,
                                                 float* __restrict__ agg1) {
    int tid  = threadIdx.x;
    int lane = tid & 63;
    int grp  = lane >> 4;                    // 0..3
    int l16  = lane & 15;
    int g0   = lane & 48;                    // group base lane (absolute in wave)
    int node = ((blockIdx.x * 256 + tid) >> 6) * 4 + grp;
    if (node >= N_NODES) return;
    int   b  = base[node];
    int   c  = cnt[node];
    float di = dinv[node];
    float4 acc = g1[(size_t)node * 16 + l16];          // self term

    for (int k0 = 0; k0 < c; k0 += 16) {
        int k = k0 + l16;
        int sidx = (k < c) ? csr_src[b + k] : 0;       // group-coalesced stage
        int nj = min(16, c - k0);
        int j = 0;
        for (; j + 4 <= nj; j += 4) {
            int s0 = __shfl(sidx, g0 + j + 0);
            int s1 = __shfl(sidx, g0 + j + 1);
            int s2 = __shfl(sidx, g0 + j + 2);
            int s3 = __shfl(sidx, g0 + j + 3);
            float4 v0 = g1[(size_t)s0 * 16 + l16];     // 4 independent 256B rows
            float4 v1 = g1[(size_t)s1 * 16 + l16];
            float4 v2 = g1[(size_t)s2 * 16 + l16];
            float4 v3 = g1[(size_t)s3 * 16 + l16];
            add4(acc, v0); add4(acc, v1); add4(acc, v2); add4(acc, v3);
        }
        for (; j < nj; ++j) {
            float4 v = g1[(size_t)__shfl(sidx, g0 + j) * 16 + l16];
            add4(acc, v);
        }
    }
    float4 bv = ((const float4*)b1)[l16];
    float4 r  = { fmaf(di, acc.x, bv.x), fmaf(di, acc.y, bv.y),
                  fmaf(di, acc.z, bv.z), fmaf(di, acc.w, bv.w) };
    ((float4*)agg1)[(size_t)node * 16 + l16] = r;
}

// ---------- GEMM2: g2[N,16] = dinv[row] * (relu(agg1)[N,64] @ W2[64,16]) ----------
__global__ __launch_bounds__(256) void k_gemm2(const float* __restrict__ hpre,
                                               const float* __restrict__ W2,
                                               const float* __restrict__ dinv,
                                               float* __restrict__ g2) {
    __shared__ float4 wlds[H_DIM * 4];                // 4 KB
    int tid = threadIdx.x;
    if (tid < H_DIM * 4) wlds[tid] = ((const float4*)W2)[tid];
    __syncthreads();

    int row = blockIdx.x * 64 + (tid >> 2);
    if (row >= N_NODES) return;
    int colq = tid & 3;
    const float4* h4 = (const float4*)(hpre + (size_t)row * H_DIM);
    float4 acc = {0.f, 0.f, 0.f, 0.f};
    #pragma unroll
    for (int k4 = 0; k4 < H_DIM / 4; ++k4) {
        float4 hv = h4[k4];
        hv.x = fmaxf(hv.x, 0.f); hv.y = fmaxf(hv.y, 0.f);
        hv.z = fmaxf(hv.z, 0.f); hv.w = fmaxf(hv.w, 0.f);
        fma4(acc, hv.x, wlds[(4 * k4 + 0) * 4 + colq]);
        fma4(acc, hv.y, wlds[(4 * k4 + 1) * 4 + colq]);
        fma4(acc, hv.z, wlds[(4 * k4 + 2) * 4 + colq]);
        fma4(acc, hv.w, wlds[(4 * k4 + 3) * 4 + colq]);
    }
    float di = dinv[row];
    acc.x *= di; acc.y *= di; acc.z *= di; acc.w *= di;
    ((float4*)(g2 + (size_t)row * C_DIM))[colq] = acc;
}

// ---------- gather layer 2: 4-lane group per node (16 nodes/wave), float4 ----------
__global__ __launch_bounds__(256) void k_gather2(const int* __restrict__ csr_src,
                                                 const int* __restrict__ base,
                                                 const int* __restrict__ cnt,
                                                 const float* __restrict__ dinv,
                                                 const float4* __restrict__ g2,   // [N][4]
                                                 const float* __restrict__ b2,
                                                 float* __restrict__ out) {
    int tid  = threadIdx.x;
    int lane = tid & 63;
    int grp  = lane >> 2;                    // 0..15
    int l4   = lane & 3;
    int g0   = lane & 60;                    // group base lane
    int node = ((blockIdx.x * 256 + tid) >> 6) * 16 + grp;
    if (node >= N_NODES) return;
    int   b  = base[node];
    int   c  = cnt[node];
    float di = dinv[node];
    float4 acc = g2[(size_t)node * 4 + l4];            // self term

    for (int k0 = 0; k0 < c; k0 += 4) {
        int k = k0 + l4;
        int sidx = (k < c) ? csr_src[b + k] : 0;
        int nj = min(4, c - k0);
        if (nj == 4) {
            int s0 = __shfl(sidx, g0 + 0);
            int s1 = __shfl(sidx, g0 + 1);
            int s2 = __shfl(sidx, g0 + 2);
            int s3 = __shfl(sidx, g0 + 3);
            float4 v0 = g2[(size_t)s0 * 4 + l4];
            float4 v1 = g2[(size_t)s1 * 4 + l4];
            float4 v2 = g2[(size_t)s2 * 4 + l4];
            float4 v3 = g2[(size_t)s3 * 4 + l4];
            add4(acc, v0); add4(acc, v1); add4(acc, v2); add4(acc, v3);
        } else {
            for (int j = 0; j < nj; ++j) {
                float4 v = g2[(size_t)__shfl(sidx, g0 + j) * 4 + l4];
                add4(acc, v);
            }
        }
    }
    float4 bv = ((const float4*)b2)[l4];
    float4 r  = { fmaf(di, acc.x, bv.x), fmaf(di, acc.y, bv.y),
                  fmaf(di, acc.z, bv.z), fmaf(di, acc.w, bv.w) };
    ((float4*)out)[(size_t)node * 4 + l4] = r;
}

extern "C" void kernel_launch(void* const* d_in, const int* in_sizes, int n_in,
                              void* d_out, int out_size, void* d_ws, size_t ws_size,
                              hipStream_t stream) {
    const float* x     = (const float*)d_in[0];
    const int*   edges = (const int*)d_in[1];              // int32 (harness converts)
    const float* W1    = (const float*)d_in[2];
    const float* b1    = (const float*)d_in[3];
    const float* W2    = (const float*)d_in[4];
    const float* b2    = (const float*)d_in[5];
    float*       out   = (float*)d_out;

    const int E = in_sizes[1] / 2;                         // 3,200,000

    // workspace (~65.4 MB):
    // region A (25.6 MB): pairs (CSR build), then g1/g2 (pairs dead after k_bnode)
    float* g1      = (float*)d_ws;                         // N*64 f32
    int2*  pairs   = (int2*)d_ws;                          // E int2 (same bytes)
    float* agg1    = g1 + (size_t)N_NODES * H_DIM;         // N*64 f32
    int*   csr_src = (int*)(agg1 + (size_t)N_NODES * H_DIM); // E
    int*   nbase   = csr_src + E;                          // N
    int*   ncnt    = nbase + N_NODES;                      // N
    float* dinv    = (float*)(ncnt + N_NODES);             // N
    int*   bkt_tot = (int*)(dinv + N_NODES);               // NBKT*16
    int*   bkt_base= bkt_tot + NBKT * BKT_PAD;             // NBKT
    int*   bkt_tail= bkt_base + NBKT;                      // NBKT*16
    float* g2      = g1;   // g1 dead after k_gather1; k_gemm2 reads only agg1

    const int nchunk = (E + CHUNK - 1) / CHUNK;            // 782

    // CSR build (bucketed counting sort by dst)
    k_zero_b <<<(NBKT * BKT_PAD + 255) / 256, 256, 0, stream>>>(bkt_tot);
    k_bhist  <<<nchunk, 256, 0, stream>>>((const int2*)edges, bkt_tot, E);
    k_bscan  <<<1, 512, 0, stream>>>(bkt_tot, bkt_base, bkt_tail);
    k_bfill  <<<nchunk, 256, 0, stream>>>((const int2*)edges, bkt_tail, pairs, E);
    k_bnode  <<<NBKT, 256, 0, stream>>>(pairs, bkt_base, csr_src, nbase, ncnt, dinv, E);

    // layer 1
    k_gemm1   <<<N_NODES / 16, 256, 0, stream>>>(x, W1, dinv, g1);
    k_gather1 <<<(N_NODES / 4 + 3) / 4 * 4 / 4, 256, 0, stream>>>(csr_src, nbase, ncnt,
                                                                  dinv, (const float4*)g1,
                                                                  b1, agg1);
    // layer 2 (relu fused into gemm2 load, dinv into epilogue)
    k_gemm2   <<<(N_NODES + 63) / 64, 256, 0, stream>>>(agg1, W2, dinv, g2);
    k_gather2 <<<(N_NODES / 16 + 3) / 4, 256, 0, stream>>>(csr_src, nbase, ncnt,
                                                           dinv, (const float4*)g2,
                                                           b2, out);
}

// Round 7
// 240.284 us; speedup vs baseline: 1.3264x; 1.3264x over previous
//
#include <hip/hip_runtime.h>

#define N_NODES 100000
#define F_IN    128
#define H_DIM   64
#define C_DIM   16
#define NBKT    391            // ceil(100000 / 256) buckets of 256 nodes (dst>>8)
#define BKT_PAD 16             // one bucket counter per 64B line
#define CHUNK   4096           // edges per block in bucket phases
#define CAP     8960           // padded bucket capacity (lambda=8192, +8.5 sigma)

__device__ __forceinline__ void fma4(float4& acc, float s, const float4& w) {
    acc.x = fmaf(s, w.x, acc.x);
    acc.y = fmaf(s, w.y, acc.y);
    acc.z = fmaf(s, w.z, acc.z);
    acc.w = fmaf(s, w.w, acc.w);
}
__device__ __forceinline__ void add4(float4& a, const float4& v) {
    a.x += v.x; a.y += v.y; a.z += v.z; a.w += v.w;
}
// f32 -> bf16 round-to-nearest-even
__device__ __forceinline__ unsigned bfr(float f) {
    unsigned u = __float_as_uint(f);
    return (u + (((u >> 16) & 1u) + 0x7FFFu)) >> 16;
}
// unpack-add: two packed bf16 pairs -> 4 f32 adds
__device__ __forceinline__ void accb(float4& a, uint2 u) {
    a.x += __uint_as_float(u.x << 16);
    a.y += __uint_as_float(u.x & 0xFFFF0000u);
    a.z += __uint_as_float(u.y << 16);
    a.w += __uint_as_float(u.y & 0xFFFF0000u);
}

// ---------- CSR build ----------
__global__ void k_zero_b(int* __restrict__ b) {
    int i = blockIdx.x * blockDim.x + threadIdx.x;
    if (i < NBKT * BKT_PAD) b[i] = 0;
}

// single pass: per-block LDS hist -> reserve bucket range -> bucket-grouped write.
// pairs packed: (src<<8) | (dst & 255); bucket = dst>>8; bucket b lives at [b*CAP, ...)
__global__ __launch_bounds__(256) void k_bfill(const int2* __restrict__ edges,
                                               int* __restrict__ bkt_tail,
                                               int* __restrict__ pairs, int E) {
    __shared__ int cnt[NBKT];
    __shared__ int row[NBKT];
    for (int t = threadIdx.x; t < NBKT; t += 256) cnt[t] = 0;
    __syncthreads();
    int base = blockIdx.x * CHUNK;
    int2 ed[CHUNK / 256];                   // 16 int2 in registers (static idx via unroll)
    #pragma unroll
    for (int i = 0; i < CHUNK / 256; ++i) {
        int e = base + i * 256 + threadIdx.x;
        if (e < E) { ed[i] = edges[e]; atomicAdd(&cnt[ed[i].y >> 8], 1); }
    }
    __syncthreads();
    for (int t = threadIdx.x; t < NBKT; t += 256)
        row[t] = cnt[t] ? atomicAdd(&bkt_tail[t * BKT_PAD], cnt[t]) : 0;
    __syncthreads();
    #pragma unroll
    for (int i = 0; i < CHUNK / 256; ++i) {
        int e = base + i * 256 + threadIdx.x;
        if (e < E) {
            int bkt = ed[i].y >> 8;
            int r   = atomicAdd(&row[bkt], 1);          // LDS atomic
            if (r < CAP) pairs[bkt * CAP + r] = (ed[i].x << 8) | (ed[i].y & 255);
        }
    }
}

// one block per bucket: node-ordered base/cnt/dinv + dense CSR scatter (padded)
__global__ __launch_bounds__(256) void k_bnode(const int* __restrict__ pairs,
                                               const int* __restrict__ bkt_tail,
                                               int* __restrict__ csr_src,
                                               int* __restrict__ node_base,
                                               int* __restrict__ node_cnt,
                                               float* __restrict__ dinv) {
    __shared__ int cnt[256];
    __shared__ int s[256];
    __shared__ int row[256];
    int b = blockIdx.x;
    int t = threadIdx.x;
    cnt[t] = 0;
    __syncthreads();
    int start = b * CAP;
    int m     = min(bkt_tail[b * BKT_PAD], CAP);
    for (int e = t; e < m; e += 256)
        atomicAdd(&cnt[pairs[start + e] & 255], 1);
    __syncthreads();
    int c = cnt[t];
    s[t] = c;
    __syncthreads();
    #pragma unroll
    for (int off = 1; off < 256; off <<= 1) {
        int u = (t >= off) ? s[t - off] : 0;
        __syncthreads();
        s[t] += u;
        __syncthreads();
    }
    int gbase = start + s[t] - c;           // positions within padded csr
    row[t] = gbase;
    int node = b * 256 + t;
    if (node < N_NODES) {
        node_base[node] = gbase;
        node_cnt[node]  = c;
        dinv[node]      = rsqrtf((float)(c + 1));   // deg = cnt + 1 (self loop)
    }
    __syncthreads();
    for (int e = t; e < m; e += 256) {
        int p   = pairs[start + e];
        int pos = atomicAdd(&row[p & 255], 1);      // LDS atomic
        csr_src[pos] = ((unsigned)p) >> 8;
    }
}

// ---------- GEMM1: g1b[N,64](bf16) = dinv[row] * (x[N,128] @ W1[128,64]) ----------
__global__ __launch_bounds__(256) void k_gemm1(const float* __restrict__ x,
                                               const float* __restrict__ W1,
                                               const float* __restrict__ dinv,
                                               uint2* __restrict__ g1b) {
    __shared__ float4 wlds[F_IN * 16];               // 32 KB
    int tid = threadIdx.x;
    const float4* w4 = (const float4*)W1;
    #pragma unroll
    for (int i = 0; i < 8; ++i) wlds[tid + 256 * i] = w4[tid + 256 * i];
    __syncthreads();

    int row  = blockIdx.x * 16 + (tid >> 4);         // N = 6250*16 exactly
    int colq = tid & 15;
    const float4* x4 = (const float4*)(x + (size_t)row * F_IN);
    float4 acc = {0.f, 0.f, 0.f, 0.f};
    #pragma unroll
    for (int k4 = 0; k4 < F_IN / 4; ++k4) {
        float4 xv = x4[k4];
        fma4(acc, xv.x, wlds[(4 * k4 + 0) * 16 + colq]);
        fma4(acc, xv.y, wlds[(4 * k4 + 1) * 16 + colq]);
        fma4(acc, xv.z, wlds[(4 * k4 + 2) * 16 + colq]);
        fma4(acc, xv.w, wlds[(4 * k4 + 3) * 16 + colq]);
    }
    float di = dinv[row];
    uint2 p;
    p.x = bfr(acc.x * di) | (bfr(acc.y * di) << 16);
    p.y = bfr(acc.z * di) | (bfr(acc.w * di) << 16);
    g1b[(size_t)row * 16 + colq] = p;
}

// ---------- gather layer 1: 16-lane group per node (4 nodes/wave), bf16 rows ----------
// agg1[i] = b1 + dinv[i] * ( g1[i] + sum_{src} g1[src] ),  g1 rows 128B bf16
__global__ __launch_bounds__(256) void k_gather1(const int* __restrict__ csr_src,
                                                 const int* __restrict__ base,
                                                 const int* __restrict__ cnt,
                                                 const float* __restrict__ dinv,
                                                 const uint2* __restrict__ g1b,  // [N][16]
                                                 const float* __restrict__ b1,
                                                 float* __restrict__ agg1) {
    int tid  = threadIdx.x;
    int lane = tid & 63;
    int grp  = lane >> 4;                    // 0..3
    int l16  = lane & 15;
    int g0   = lane & 48;                    // group base lane (absolute in wave)
    int node = ((blockIdx.x * 256 + tid) >> 6) * 4 + grp;
    if (node >= N_NODES) return;
    int   b  = base[node];
    int   c  = cnt[node];
    float di = dinv[node];
    float4 acc = {0.f, 0.f, 0.f, 0.f};
    accb(acc, g1b[(size_t)node * 16 + l16]);           // self term

    for (int k0 = 0; k0 < c; k0 += 16) {
        int k = k0 + l16;
        int sidx = (k < c) ? csr_src[b + k] : 0;       // group-coalesced stage
        int nj = min(16, c - k0);
        int j = 0;
        for (; j + 4 <= nj; j += 4) {
            int s0 = __shfl(sidx, g0 + j + 0);
            int s1 = __shfl(sidx, g0 + j + 1);
            int s2 = __shfl(sidx, g0 + j + 2);
            int s3 = __shfl(sidx, g0 + j + 3);
            uint2 u0 = g1b[(size_t)s0 * 16 + l16];     // 4 independent 128B rows
            uint2 u1 = g1b[(size_t)s1 * 16 + l16];
            uint2 u2 = g1b[(size_t)s2 * 16 + l16];
            uint2 u3 = g1b[(size_t)s3 * 16 + l16];
            accb(acc, u0); accb(acc, u1); accb(acc, u2); accb(acc, u3);
        }
        for (; j < nj; ++j) {
            accb(acc, g1b[(size_t)__shfl(sidx, g0 + j) * 16 + l16]);
        }
    }
    float4 bv = ((const float4*)b1)[l16];
    float4 r  = { fmaf(di, acc.x, bv.x), fmaf(di, acc.y, bv.y),
                  fmaf(di, acc.z, bv.z), fmaf(di, acc.w, bv.w) };
    ((float4*)agg1)[(size_t)node * 16 + l16] = r;
}

// ---------- GEMM2: g2[N,16] = dinv[row] * (relu(agg1)[N,64] @ W2[64,16]) ----------
__global__ __launch_bounds__(256) void k_gemm2(const float* __restrict__ hpre,
                                               const float* __restrict__ W2,
                                               const float* __restrict__ dinv,
                                               float* __restrict__ g2) {
    __shared__ float4 wlds[H_DIM * 4];                // 4 KB
    int tid = threadIdx.x;
    if (tid < H_DIM * 4) wlds[tid] = ((const float4*)W2)[tid];
    __syncthreads();

    int row = blockIdx.x * 64 + (tid >> 2);
    if (row >= N_NODES) return;
    int colq = tid & 3;
    const float4* h4 = (const float4*)(hpre + (size_t)row * H_DIM);
    float4 acc = {0.f, 0.f, 0.f, 0.f};
    #pragma unroll
    for (int k4 = 0; k4 < H_DIM / 4; ++k4) {
        float4 hv = h4[k4];
        hv.x = fmaxf(hv.x, 0.f); hv.y = fmaxf(hv.y, 0.f);
        hv.z = fmaxf(hv.z, 0.f); hv.w = fmaxf(hv.w, 0.f);
        fma4(acc, hv.x, wlds[(4 * k4 + 0) * 4 + colq]);
        fma4(acc, hv.y, wlds[(4 * k4 + 1) * 4 + colq]);
        fma4(acc, hv.z, wlds[(4 * k4 + 2) * 4 + colq]);
        fma4(acc, hv.w, wlds[(4 * k4 + 3) * 4 + colq]);
    }
    float di = dinv[row];
    acc.x *= di; acc.y *= di; acc.z *= di; acc.w *= di;
    ((float4*)(g2 + (size_t)row * C_DIM))[colq] = acc;
}

// ---------- gather layer 2: 4-lane group per node (16 nodes/wave), f32 ----------
__global__ __launch_bounds__(256) void k_gather2(const int* __restrict__ csr_src,
                                                 const int* __restrict__ base,
                                                 const int* __restrict__ cnt,
                                                 const float* __restrict__ dinv,
                                                 const float4* __restrict__ g2,   // [N][4]
                                                 const float* __restrict__ b2,
                                                 float* __restrict__ out) {
    int tid  = threadIdx.x;
    int lane = tid & 63;
    int grp  = lane >> 2;                    // 0..15
    int l4   = lane & 3;
    int g0   = lane & 60;                    // group base lane
    int node = ((blockIdx.x * 256 + tid) >> 6) * 16 + grp;
    if (node >= N_NODES) return;
    int   b  = base[node];
    int   c  = cnt[node];
    float di = dinv[node];
    float4 acc = g2[(size_t)node * 4 + l4];            // self term

    for (int k0 = 0; k0 < c; k0 += 4) {
        int k = k0 + l4;
        int sidx = (k < c) ? csr_src[b + k] : 0;
        int nj = min(4, c - k0);
        if (nj == 4) {
            int s0 = __shfl(sidx, g0 + 0);
            int s1 = __shfl(sidx, g0 + 1);
            int s2 = __shfl(sidx, g0 + 2);
            int s3 = __shfl(sidx, g0 + 3);
            float4 v0 = g2[(size_t)s0 * 4 + l4];
            float4 v1 = g2[(size_t)s1 * 4 + l4];
            float4 v2 = g2[(size_t)s2 * 4 + l4];
            float4 v3 = g2[(size_t)s3 * 4 + l4];
            add4(acc, v0); add4(acc, v1); add4(acc, v2); add4(acc, v3);
        } else {
            for (int j = 0; j < nj; ++j) {
                float4 v = g2[(size_t)__shfl(sidx, g0 + j) * 4 + l4];
                add4(acc, v);
            }
        }
    }
    float4 bv = ((const float4*)b2)[l4];
    float4 r  = { fmaf(di, acc.x, bv.x), fmaf(di, acc.y, bv.y),
                  fmaf(di, acc.z, bv.z), fmaf(di, acc.w, bv.w) };
    ((float4*)out)[(size_t)node * 4 + l4] = r;
}

extern "C" void kernel_launch(void* const* d_in, const int* in_sizes, int n_in,
                              void* d_out, int out_size, void* d_ws, size_t ws_size,
                              hipStream_t stream) {
    const float* x     = (const float*)d_in[0];
    const int*   edges = (const int*)d_in[1];              // int32 (harness converts)
    const float* W1    = (const float*)d_in[2];
    const float* b1    = (const float*)d_in[3];
    const float* W2    = (const float*)d_in[4];
    const float* b2    = (const float*)d_in[5];
    float*       out   = (float*)d_out;

    const int E = in_sizes[1] / 2;                         // 3,200,000

    // workspace (~55 MB):
    // region A (14.0 MB): pairs (build) -> g1b (bf16, 12.8 MB) -> g2 (f32, 6.4 MB)
    int*   pairs   = (int*)d_ws;                           // NBKT*CAP ints
    uint2* g1b     = (uint2*)d_ws;                         // N*16 uint2 (bf16 rows)
    float* g2      = (float*)d_ws;                         // N*16 f32
    float* agg1    = (float*)d_ws + (size_t)NBKT * CAP;    // N*64 f32
    int*   csr_src = (int*)(agg1 + (size_t)N_NODES * H_DIM); // NBKT*CAP (padded)
    int*   nbase   = csr_src + (size_t)NBKT * CAP;         // N
    int*   ncnt    = nbase + N_NODES;                      // N
    float* dinv    = (float*)(ncnt + N_NODES);             // N
    int*   bkt_tail= (int*)(dinv + N_NODES);               // NBKT*16

    const int nchunk = (E + CHUNK - 1) / CHUNK;            // 782

    // CSR build (single-pass padded-bucket sort by dst)
    k_zero_b <<<(NBKT * BKT_PAD + 255) / 256, 256, 0, stream>>>(bkt_tail);
    k_bfill  <<<nchunk, 256, 0, stream>>>((const int2*)edges, bkt_tail, pairs, E);
    k_bnode  <<<NBKT, 256, 0, stream>>>(pairs, bkt_tail, csr_src, nbase, ncnt, dinv);

    // layer 1
    k_gemm1   <<<N_NODES / 16, 256, 0, stream>>>(x, W1, dinv, g1b);
    k_gather1 <<<6250, 256, 0, stream>>>(csr_src, nbase, ncnt, dinv, g1b, b1, agg1);

    // layer 2 (relu fused into gemm2 load, dinv into epilogue)
    k_gemm2   <<<(N_NODES + 63) / 64, 256, 0, stream>>>(agg1, W2, dinv, g2);
    k_gather2 <<<1563, 256, 0, stream>>>(csr_src, nbase, ncnt, dinv, (const float4*)g2,
                                         b2, out);
}

// Round 8
// 213.442 us; speedup vs baseline: 1.4932x; 1.1258x over previous
//
#include <hip/hip_runtime.h>

#define N_NODES 100000
#define F_IN    128
#define H_DIM   64
#define C_DIM   16
#define NBKT    391            // ceil(100000 / 256) buckets of 256 nodes (dst>>8)
#define BKT_PAD 16             // one bucket counter per 64B line
#define CHUNK   4096           // edges per block in bucket phases
#define CAP     8960           // padded bucket capacity (lambda=8192, +8.5 sigma)

__device__ __forceinline__ void fma4(float4& acc, float s, const float4& w) {
    acc.x = fmaf(s, w.x, acc.x);
    acc.y = fmaf(s, w.y, acc.y);
    acc.z = fmaf(s, w.z, acc.z);
    acc.w = fmaf(s, w.w, acc.w);
}
// f32 -> bf16 round-to-nearest-even
__device__ __forceinline__ unsigned bfr(float f) {
    unsigned u = __float_as_uint(f);
    return (u + (((u >> 16) & 1u) + 0x7FFFu)) >> 16;
}
// unpack-add: two packed bf16 pairs -> 4 f32 adds
__device__ __forceinline__ void accb(float4& a, uint2 u) {
    a.x += __uint_as_float(u.x << 16);
    a.y += __uint_as_float(u.x & 0xFFFF0000u);
    a.z += __uint_as_float(u.y << 16);
    a.w += __uint_as_float(u.y & 0xFFFF0000u);
}

// ---------- CSR build ----------
__global__ void k_zero_b(int* __restrict__ b) {
    int i = blockIdx.x * blockDim.x + threadIdx.x;
    if (i < NBKT * BKT_PAD) b[i] = 0;
}

// single pass: per-block LDS hist -> reserve bucket range -> bucket-grouped write.
// pairs packed: (src<<8) | (dst & 255); bucket = dst>>8; bucket b lives at [b*CAP, ...)
__global__ __launch_bounds__(256) void k_bfill(const int2* __restrict__ edges,
                                               int* __restrict__ bkt_tail,
                                               int* __restrict__ pairs, int E) {
    __shared__ int cnt[NBKT];
    __shared__ int row[NBKT];
    for (int t = threadIdx.x; t < NBKT; t += 256) cnt[t] = 0;
    __syncthreads();
    int base = blockIdx.x * CHUNK;
    int2 ed[CHUNK / 256];                   // 16 int2 in registers (static idx via unroll)
    #pragma unroll
    for (int i = 0; i < CHUNK / 256; ++i) {
        int e = base + i * 256 + threadIdx.x;
        if (e < E) { ed[i] = edges[e]; atomicAdd(&cnt[ed[i].y >> 8], 1); }
    }
    __syncthreads();
    for (int t = threadIdx.x; t < NBKT; t += 256)
        row[t] = cnt[t] ? atomicAdd(&bkt_tail[t * BKT_PAD], cnt[t]) : 0;
    __syncthreads();
    #pragma unroll
    for (int i = 0; i < CHUNK / 256; ++i) {
        int e = base + i * 256 + threadIdx.x;
        if (e < E) {
            int bkt = ed[i].y >> 8;
            int r   = atomicAdd(&row[bkt], 1);          // LDS atomic
            if (r < CAP) pairs[bkt * CAP + r] = (ed[i].x << 8) | (ed[i].y & 255);
        }
    }
}

// one block per bucket: stage pairs in LDS once, hist+scan, scatter into LDS csr
// image, coalesced copy-out. node-ordered base/cnt/dinv as side products.
__global__ __launch_bounds__(256) void k_bnode(const int* __restrict__ pairs,
                                               const int* __restrict__ bkt_tail,
                                               int* __restrict__ csr_src,
                                               int* __restrict__ node_base,
                                               int* __restrict__ node_cnt,
                                               float* __restrict__ dinv) {
    __shared__ int sp[CAP];                 // 35 KB staged pairs
    __shared__ int sc[CAP];                 // 35 KB staged csr (src ids, local pos)
    __shared__ int cnt[256];
    __shared__ int s[256];
    __shared__ int row[256];
    int b = blockIdx.x;
    int t = threadIdx.x;
    cnt[t] = 0;
    __syncthreads();
    int start = b * CAP;
    int m     = min(bkt_tail[b * BKT_PAD], CAP);
    for (int e = t; e < m; e += 256) {
        int p = pairs[start + e];           // coalesced, single global read
        sp[e] = p;
        atomicAdd(&cnt[p & 255], 1);
    }
    __syncthreads();
    int c = cnt[t];
    s[t] = c;
    __syncthreads();
    #pragma unroll
    for (int off = 1; off < 256; off <<= 1) {
        int u = (t >= off) ? s[t - off] : 0;
        __syncthreads();
        s[t] += u;
        __syncthreads();
    }
    row[t] = s[t] - c;                      // local position base within bucket
    int node = b * 256 + t;
    if (node < N_NODES) {
        node_base[node] = start + s[t] - c;
        node_cnt[node]  = c;
        dinv[node]      = rsqrtf((float)(c + 1));   // deg = cnt + 1 (self loop)
    }
    __syncthreads();
    for (int e = t; e < m; e += 256) {
        int p   = sp[e];
        int pos = atomicAdd(&row[p & 255], 1);      // LDS atomic, local pos
        sc[pos] = ((unsigned)p) >> 8;
    }
    __syncthreads();
    for (int e = t; e < m; e += 256)
        csr_src[start + e] = sc[e];                 // coalesced copy-out
}

// ---------- GEMM1: g1b[N,64](bf16) = dinv[row] * (x[N,128] @ W1[128,64]) ----------
__global__ __launch_bounds__(256) void k_gemm1(const float* __restrict__ x,
                                               const float* __restrict__ W1,
                                               const float* __restrict__ dinv,
                                               uint2* __restrict__ g1b) {
    __shared__ float4 wlds[F_IN * 16];               // 32 KB
    int tid = threadIdx.x;
    const float4* w4 = (const float4*)W1;
    #pragma unroll
    for (int i = 0; i < 8; ++i) wlds[tid + 256 * i] = w4[tid + 256 * i];
    __syncthreads();

    int row  = blockIdx.x * 16 + (tid >> 4);         // N = 6250*16 exactly
    int colq = tid & 15;
    const float4* x4 = (const float4*)(x + (size_t)row * F_IN);
    float4 acc = {0.f, 0.f, 0.f, 0.f};
    #pragma unroll
    for (int k4 = 0; k4 < F_IN / 4; ++k4) {
        float4 xv = x4[k4];
        fma4(acc, xv.x, wlds[(4 * k4 + 0) * 16 + colq]);
        fma4(acc, xv.y, wlds[(4 * k4 + 1) * 16 + colq]);
        fma4(acc, xv.z, wlds[(4 * k4 + 2) * 16 + colq]);
        fma4(acc, xv.w, wlds[(4 * k4 + 3) * 16 + colq]);
    }
    float di = dinv[row];
    uint2 p;
    p.x = bfr(acc.x * di) | (bfr(acc.y * di) << 16);
    p.y = bfr(acc.z * di) | (bfr(acc.w * di) << 16);
    g1b[(size_t)row * 16 + colq] = p;
}

// ---------- gather layer 1: 16-lane group per node (4 nodes/wave), bf16 rows ----------
// agg1[i] = b1 + dinv[i] * ( g1[i] + sum_{src} g1[src] ),  g1 rows 128B bf16
__global__ __launch_bounds__(256) void k_gather1(const int* __restrict__ csr_src,
                                                 const int* __restrict__ base,
                                                 const int* __restrict__ cnt,
                                                 const float* __restrict__ dinv,
                                                 const uint2* __restrict__ g1b,  // [N][16]
                                                 const float* __restrict__ b1,
                                                 float* __restrict__ agg1) {
    int tid  = threadIdx.x;
    int lane = tid & 63;
    int grp  = lane >> 4;                    // 0..3
    int l16  = lane & 15;
    int g0   = lane & 48;                    // group base lane (absolute in wave)
    int node = ((blockIdx.x * 256 + tid) >> 6) * 4 + grp;
    if (node >= N_NODES) return;
    int   b  = base[node];
    int   c  = cnt[node];
    float di = dinv[node];
    float4 acc = {0.f, 0.f, 0.f, 0.f};
    accb(acc, g1b[(size_t)node * 16 + l16]);           // self term

    for (int k0 = 0; k0 < c; k0 += 16) {
        int k = k0 + l16;
        int sidx = (k < c) ? csr_src[b + k] : 0;       // group-coalesced stage
        int nj = min(16, c - k0);
        int j = 0;
        for (; j + 4 <= nj; j += 4) {
            int s0 = __shfl(sidx, g0 + j + 0);
            int s1 = __shfl(sidx, g0 + j + 1);
            int s2 = __shfl(sidx, g0 + j + 2);
            int s3 = __shfl(sidx, g0 + j + 3);
            uint2 u0 = g1b[(size_t)s0 * 16 + l16];     // 4 independent 128B rows
            uint2 u1 = g1b[(size_t)s1 * 16 + l16];
            uint2 u2 = g1b[(size_t)s2 * 16 + l16];
            uint2 u3 = g1b[(size_t)s3 * 16 + l16];
            accb(acc, u0); accb(acc, u1); accb(acc, u2); accb(acc, u3);
        }
        for (; j < nj; ++j) {
            accb(acc, g1b[(size_t)__shfl(sidx, g0 + j) * 16 + l16]);
        }
    }
    float4 bv = ((const float4*)b1)[l16];
    float4 r  = { fmaf(di, acc.x, bv.x), fmaf(di, acc.y, bv.y),
                  fmaf(di, acc.z, bv.z), fmaf(di, acc.w, bv.w) };
    ((float4*)agg1)[(size_t)node * 16 + l16] = r;
}

// ---------- GEMM2: g2b[N,16](bf16) = dinv[row] * (relu(agg1)[N,64] @ W2[64,16]) ----------
__global__ __launch_bounds__(256) void k_gemm2(const float* __restrict__ hpre,
                                               const float* __restrict__ W2,
                                               const float* __restrict__ dinv,
                                               uint2* __restrict__ g2b) {
    __shared__ float4 wlds[H_DIM * 4];                // 4 KB
    int tid = threadIdx.x;
    if (tid < H_DIM * 4) wlds[tid] = ((const float4*)W2)[tid];
    __syncthreads();

    int row = blockIdx.x * 64 + (tid >> 2);
    if (row >= N_NODES) return;
    int colq = tid & 3;
    const float4* h4 = (const float4*)(hpre + (size_t)row * H_DIM);
    float4 acc = {0.f, 0.f, 0.f, 0.f};
    #pragma unroll
    for (int k4 = 0; k4 < H_DIM / 4; ++k4) {
        float4 hv = h4[k4];
        hv.x = fmaxf(hv.x, 0.f); hv.y = fmaxf(hv.y, 0.f);
        hv.z = fmaxf(hv.z, 0.f); hv.w = fmaxf(hv.w, 0.f);
        fma4(acc, hv.x, wlds[(4 * k4 + 0) * 4 + colq]);
        fma4(acc, hv.y, wlds[(4 * k4 + 1) * 4 + colq]);
        fma4(acc, hv.z, wlds[(4 * k4 + 2) * 4 + colq]);
        fma4(acc, hv.w, wlds[(4 * k4 + 3) * 4 + colq]);
    }
    float di = dinv[row];
    uint2 p;
    p.x = bfr(acc.x * di) | (bfr(acc.y * di) << 16);
    p.y = bfr(acc.z * di) | (bfr(acc.w * di) << 16);
    g2b[(size_t)row * 4 + colq] = p;
}

// ---------- gather layer 2: 4-lane group per node (16 nodes/wave), bf16 rows ----------
__global__ __launch_bounds__(256) void k_gather2(const int* __restrict__ csr_src,
                                                 const int* __restrict__ base,
                                                 const int* __restrict__ cnt,
                                                 const float* __restrict__ dinv,
                                                 const uint2* __restrict__ g2b,   // [N][4]
                                                 const float* __restrict__ b2,
                                                 float* __restrict__ out) {
    int tid  = threadIdx.x;
    int lane = tid & 63;
    int grp  = lane >> 2;                    // 0..15
    int l4   = lane & 3;
    int g0   = lane & 60;                    // group base lane
    int node = ((blockIdx.x * 256 + tid) >> 6) * 16 + grp;
    if (node >= N_NODES) return;
    int   b  = base[node];
    int   c  = cnt[node];
    float di = dinv[node];
    float4 acc = {0.f, 0.f, 0.f, 0.f};
    accb(acc, g2b[(size_t)node * 4 + l4]);             // self term

    for (int k0 = 0; k0 < c; k0 += 4) {
        int k = k0 + l4;
        int sidx = (k < c) ? csr_src[b + k] : 0;
        int nj = min(4, c - k0);
        if (nj == 4) {
            int s0 = __shfl(sidx, g0 + 0);
            int s1 = __shfl(sidx, g0 + 1);
            int s2 = __shfl(sidx, g0 + 2);
            int s3 = __shfl(sidx, g0 + 3);
            uint2 u0 = g2b[(size_t)s0 * 4 + l4];       // 4 independent 32B rows
            uint2 u1 = g2b[(size_t)s1 * 4 + l4];
            uint2 u2 = g2b[(size_t)s2 * 4 + l4];
            uint2 u3 = g2b[(size_t)s3 * 4 + l4];
            accb(acc, u0); accb(acc, u1); accb(acc, u2); accb(acc, u3);
        } else {
            for (int j = 0; j < nj; ++j)
                accb(acc, g2b[(size_t)__shfl(sidx, g0 + j) * 4 + l4]);
        }
    }
    float4 bv = ((const float4*)b2)[l4];
    float4 r  = { fmaf(di, acc.x, bv.x), fmaf(di, acc.y, bv.y),
                  fmaf(di, acc.z, bv.z), fmaf(di, acc.w, bv.w) };
    ((float4*)out)[(size_t)node * 4 + l4] = r;
}

extern "C" void kernel_launch(void* const* d_in, const int* in_sizes, int n_in,
                              void* d_out, int out_size, void* d_ws, size_t ws_size,
                              hipStream_t stream) {
    const float* x     = (const float*)d_in[0];
    const int*   edges = (const int*)d_in[1];              // int32 (harness converts)
    const float* W1    = (const float*)d_in[2];
    const float* b1    = (const float*)d_in[3];
    const float* W2    = (const float*)d_in[4];
    const float* b2    = (const float*)d_in[5];
    float*       out   = (float*)d_out;

    const int E = in_sizes[1] / 2;                         // 3,200,000

    // workspace (~55 MB):
    // region A (14.0 MB): pairs (build) -> g1b (bf16, 12.8 MB) -> g2b (bf16, 3.2 MB)
    int*   pairs   = (int*)d_ws;                           // NBKT*CAP ints
    uint2* g1b     = (uint2*)d_ws;                         // N*16 uint2 (bf16 rows)
    uint2* g2b     = (uint2*)d_ws;                         // N*4  uint2 (bf16 rows)
    float* agg1    = (float*)d_ws + (size_t)NBKT * CAP;    // N*64 f32
    int*   csr_src = (int*)(agg1 + (size_t)N_NODES * H_DIM); // NBKT*CAP (padded)
    int*   nbase   = csr_src + (size_t)NBKT * CAP;         // N
    int*   ncnt    = nbase + N_NODES;                      // N
    float* dinv    = (float*)(ncnt + N_NODES);             // N
    int*   bkt_tail= (int*)(dinv + N_NODES);               // NBKT*16

    const int nchunk = (E + CHUNK - 1) / CHUNK;            // 782

    // CSR build (single-pass padded-bucket sort by dst)
    k_zero_b <<<(NBKT * BKT_PAD + 255) / 256, 256, 0, stream>>>(bkt_tail);
    k_bfill  <<<nchunk, 256, 0, stream>>>((const int2*)edges, bkt_tail, pairs, E);
    k_bnode  <<<NBKT, 256, 0, stream>>>(pairs, bkt_tail, csr_src, nbase, ncnt, dinv);

    // layer 1
    k_gemm1   <<<N_NODES / 16, 256, 0, stream>>>(x, W1, dinv, g1b);
    k_gather1 <<<6250, 256, 0, stream>>>(csr_src, nbase, ncnt, dinv, g1b, b1, agg1);

    // layer 2 (relu fused into gemm2 load, dinv into epilogue)
    k_gemm2   <<<(N_NODES + 63) / 64, 256, 0, stream>>>(agg1, W2, dinv, g2b);
    k_gather2 <<<1563, 256, 0, stream>>>(csr_src, nbase, ncnt, dinv, g2b, b2, out);
}

// Round 10
// 202.177 us; speedup vs baseline: 1.5764x; 1.0557x over previous
//
#include <hip/hip_runtime.h>

#define N_NODES 100000
#define F_IN    128
#define H_DIM   64
#define C_DIM   16
#define NBKT    391            // ceil(100000 / 256) buckets of 256 nodes (dst>>8)
#define BKT_PAD 16             // one bucket counter per 64B line
#define CHUNK   4096           // edges per block in bucket phases
#define CAP     8960           // padded bucket capacity (lambda=8192, +8.5 sigma)

__device__ __forceinline__ void fma4(float4& acc, float s, const float4& w) {
    acc.x = fmaf(s, w.x, acc.x);
    acc.y = fmaf(s, w.y, acc.y);
    acc.z = fmaf(s, w.z, acc.z);
    acc.w = fmaf(s, w.w, acc.w);
}
// f32 -> bf16 round-to-nearest-even
__device__ __forceinline__ unsigned bfr(float f) {
    unsigned u = __float_as_uint(f);
    return (u + (((u >> 16) & 1u) + 0x7FFFu)) >> 16;
}
// unpack-add: two packed bf16 pairs -> 4 f32 adds
__device__ __forceinline__ void accb(float4& a, uint2 u) {
    a.x += __uint_as_float(u.x << 16);
    a.y += __uint_as_float(u.x & 0xFFFF0000u);
    a.z += __uint_as_float(u.y << 16);
    a.w += __uint_as_float(u.y & 0xFFFF0000u);
}

// ---------- CSR build ----------
__global__ void k_zero_b(int* __restrict__ b) {
    int i = blockIdx.x * blockDim.x + threadIdx.x;
    if (i < NBKT * BKT_PAD) b[i] = 0;
}

// single pass: LDS hist (rank captured from atomic return) -> reserve bucket
// range -> bucket-grouped write. pairs packed: (src<<8) | (dst & 255)
__global__ __launch_bounds__(256) void k_bfill(const int2* __restrict__ edges,
                                               int* __restrict__ bkt_tail,
                                               int* __restrict__ pairs, int E) {
    __shared__ int cnt[NBKT];
    __shared__ int row[NBKT];
    for (int t = threadIdx.x; t < NBKT; t += 256) cnt[t] = 0;
    __syncthreads();
    int base = blockIdx.x * CHUNK;
    int2 ed[CHUNK / 256];                   // 16 int2 in registers (static idx via unroll)
    int  rk[CHUNK / 256];                   // local rank within (block, bucket)
    #pragma unroll
    for (int i = 0; i < CHUNK / 256; ++i) {
        int e = base + i * 256 + threadIdx.x;
        if (e < E) {
            ed[i] = edges[e];
            rk[i] = atomicAdd(&cnt[ed[i].y >> 8], 1);   // rank = pre-increment value
        }
    }
    __syncthreads();
    for (int t = threadIdx.x; t < NBKT; t += 256)
        row[t] = cnt[t] ? atomicAdd(&bkt_tail[t * BKT_PAD], cnt[t]) : 0;
    __syncthreads();
    #pragma unroll
    for (int i = 0; i < CHUNK / 256; ++i) {
        int e = base + i * 256 + threadIdx.x;
        if (e < E) {
            int bkt = ed[i].y >> 8;
            int pos = row[bkt] + rk[i];                 // no second atomic pass
            if (pos < CAP) pairs[bkt * CAP + pos] = (ed[i].x << 8) | (ed[i].y & 255);
        }
    }
}

// one block per bucket: stage pairs in LDS once, hist+scan, scatter into LDS csr
// image, coalesced copy-out. node-ordered base/cnt/dinv as side products.
__global__ __launch_bounds__(256) void k_bnode(const int* __restrict__ pairs,
                                               const int* __restrict__ bkt_tail,
                                               int* __restrict__ csr_src,
                                               int* __restrict__ node_base,
                                               int* __restrict__ node_cnt,
                                               float* __restrict__ dinv) {
    __shared__ int sp[CAP];                 // 35 KB staged pairs
    __shared__ int sc[CAP];                 // 35 KB staged csr (src ids, local pos)
    __shared__ int cnt[256];
    __shared__ int s[256];
    __shared__ int row[256];
    int b = blockIdx.x;
    int t = threadIdx.x;
    cnt[t] = 0;
    __syncthreads();
    int start = b * CAP;
    int m     = min(bkt_tail[b * BKT_PAD], CAP);
    for (int e = t; e < m; e += 256) {
        int p = pairs[start + e];           // coalesced, single global read
        sp[e] = p;
        atomicAdd(&cnt[p & 255], 1);
    }
    __syncthreads();
    int c = cnt[t];
    s[t] = c;
    __syncthreads();
    #pragma unroll
    for (int off = 1; off < 256; off <<= 1) {
        int u = (t >= off) ? s[t - off] : 0;
        __syncthreads();
        s[t] += u;
        __syncthreads();
    }
    row[t] = s[t] - c;                      // local position base within bucket
    int node = b * 256 + t;
    if (node < N_NODES) {
        node_base[node] = start + s[t] - c;
        node_cnt[node]  = c;
        dinv[node]      = rsqrtf((float)(c + 1));   // deg = cnt + 1 (self loop)
    }
    __syncthreads();
    for (int e = t; e < m; e += 256) {
        int p   = sp[e];
        int pos = atomicAdd(&row[p & 255], 1);      // LDS atomic, local pos
        sc[pos] = ((unsigned)p) >> 8;
    }
    __syncthreads();
    for (int e = t; e < m; e += 256)
        csr_src[start + e] = sc[e];                 // coalesced copy-out
}

// ---------- GEMM1: g1b[N,64](bf16) = dinv[row] * (x[N,128] @ W1[128,64]) ----------
__global__ __launch_bounds__(256) void k_gemm1(const float* __restrict__ x,
                                               const float* __restrict__ W1,
                                               const float* __restrict__ dinv,
                                               uint2* __restrict__ g1b) {
    __shared__ float4 wlds[F_IN * 16];               // 32 KB
    int tid = threadIdx.x;
    const float4* w4 = (const float4*)W1;
    #pragma unroll
    for (int i = 0; i < 8; ++i) wlds[tid + 256 * i] = w4[tid + 256 * i];
    __syncthreads();

    int row  = blockIdx.x * 16 + (tid >> 4);         // N = 6250*16 exactly
    int colq = tid & 15;
    const float4* x4 = (const float4*)(x + (size_t)row * F_IN);
    float4 acc = {0.f, 0.f, 0.f, 0.f};
    #pragma unroll
    for (int k4 = 0; k4 < F_IN / 4; ++k4) {
        float4 xv = x4[k4];
        fma4(acc, xv.x, wlds[(4 * k4 + 0) * 16 + colq]);
        fma4(acc, xv.y, wlds[(4 * k4 + 1) * 16 + colq]);
        fma4(acc, xv.z, wlds[(4 * k4 + 2) * 16 + colq]);
        fma4(acc, xv.w, wlds[(4 * k4 + 3) * 16 + colq]);
    }
    float di = dinv[row];
    uint2 p;
    p.x = bfr(acc.x * di) | (bfr(acc.y * di) << 16);
    p.y = bfr(acc.z * di) | (bfr(acc.w * di) << 16);
    g1b[(size_t)row * 16 + colq] = p;
}

// ---------- fused gather1 + bias + relu + GEMM2 ----------
// per node i (16-lane group): acc = g1[i] + sum_src g1[src]        (bf16 rows)
//   y = di * relu(b1 + di*acc)   (y holds di-prescale for layer 2)
//   g2b[i] = bf16( y @ W2 )      via LDS transpose of y + W2^T in LDS
__global__ __launch_bounds__(256) void k_gather1(const int* __restrict__ csr_src,
                                                 const int* __restrict__ base,
                                                 const int* __restrict__ cnt,
                                                 const float* __restrict__ dinv,
                                                 const uint2* __restrict__ g1b,  // [N][16]
                                                 const float* __restrict__ b1,
                                                 const float* __restrict__ W2,   // [64][16]
                                                 uint2* __restrict__ g2b) {      // [N][4]
    __shared__ float  w2t[16 * 68];          // W2^T, rows padded to 68 floats
    __shared__ float4 ysh[4][68];            // per-wave y staging, 17-f4 group stride
    int tid = threadIdx.x;
    #pragma unroll
    for (int i = 0; i < 4; ++i) {
        int idx = i * 256 + tid;             // idx = f*16 + j
        w2t[(idx & 15) * 68 + (idx >> 4)] = W2[idx];
    }
    __syncthreads();

    int lane = tid & 63;
    int wv   = tid >> 6;                     // wave in block
    int grp  = lane >> 4;                    // 0..3
    int l16  = lane & 15;
    int g0   = lane & 48;                    // group base lane (absolute in wave)
    int node = ((blockIdx.x * 256 + tid) >> 6) * 4 + grp;   // exact: 25000 waves * 4
    int   b  = base[node];
    int   c  = cnt[node];
    float di = dinv[node];
    float4 acc = {0.f, 0.f, 0.f, 0.f};
    accb(acc, g1b[(size_t)node * 16 + l16]);           // self term

    for (int k0 = 0; k0 < c; k0 += 16) {
        int k = k0 + l16;
        int sidx = (k < c) ? csr_src[b + k] : 0;       // group-coalesced stage
        int nj = min(16, c - k0);
        int j = 0;
        for (; j + 4 <= nj; j += 4) {
            int s0 = __shfl(sidx, g0 + j + 0);
            int s1 = __shfl(sidx, g0 + j + 1);
            int s2 = __shfl(sidx, g0 + j + 2);
            int s3 = __shfl(sidx, g0 + j + 3);
            uint2 u0 = g1b[(size_t)s0 * 16 + l16];     // 4 independent 128B rows
            uint2 u1 = g1b[(size_t)s1 * 16 + l16];
            uint2 u2 = g1b[(size_t)s2 * 16 + l16];
            uint2 u3 = g1b[(size_t)s3 * 16 + l16];
            accb(acc, u0); accb(acc, u1); accb(acc, u2); accb(acc, u3);
        }
        for (; j < nj; ++j) {
            accb(acc, g1b[(size_t)__shfl(sidx, g0 + j) * 16 + l16]);
        }
    }

    // epilogue: y = di*relu(b1 + di*acc), transpose via LDS, y @ W2 -> g2b
    float4 bv = ((const float4*)b1)[l16];
    float4 y;
    y.x = fmaxf(fmaf(di, acc.x, bv.x), 0.f) * di;
    y.y = fmaxf(fmaf(di, acc.y, bv.y), 0.f) * di;
    y.z = fmaxf(fmaf(di, acc.z, bv.z), 0.f) * di;
    y.w = fmaxf(fmaf(di, acc.w, bv.w), 0.f) * di;
    ysh[wv][grp * 17 + l16] = y;             // wave-internal, DS-pipe ordered

    float o = 0.f;                           // this lane's output column j = l16
    #pragma unroll
    for (int f4 = 0; f4 < 16; ++f4) {
        float4 yv = ysh[wv][grp * 17 + f4];            // broadcast within group
        const float4* wr = (const float4*)&w2t[l16 * 68 + f4 * 4];
        float4 wv4 = *wr;                              // 2 lanes/bank: free
        o = fmaf(yv.x, wv4.x, o);
        o = fmaf(yv.y, wv4.y, o);
        o = fmaf(yv.z, wv4.z, o);
        o = fmaf(yv.w, wv4.w, o);
    }
    float o1 = __shfl_down(o, 1);
    float o2 = __shfl_down(o, 2);
    float o3 = __shfl_down(o, 3);
    if ((l16 & 3) == 0) {
        uint2 pk;
        pk.x = bfr(o)  | (bfr(o1) << 16);
        pk.y = bfr(o2) | (bfr(o3) << 16);
        g2b[(size_t)node * 4 + (l16 >> 2)] = pk;
    }
}

// ---------- gather layer 2: 4-lane group per node (16 nodes/wave), bf16 rows ----------
__global__ __launch_bounds__(256) void k_gather2(const int* __restrict__ csr_src,
                                                 const int* __restrict__ base,
                                                 const int* __restrict__ cnt,
                                                 const float* __restrict__ dinv,
                                                 const uint2* __restrict__ g2b,   // [N][4]
                                                 const float* __restrict__ b2,
                                                 float* __restrict__ out) {
    int tid  = threadIdx.x;
    int lane = tid & 63;
    int grp  = lane >> 2;                    // 0..15
    int l4   = lane & 3;
    int g0   = lane & 60;                    // group base lane
    int node = ((blockIdx.x * 256 + tid) >> 6) * 16 + grp;
    if (node >= N_NODES) return;
    int   b  = base[node];
    int   c  = cnt[node];
    float di = dinv[node];
    float4 acc = {0.f, 0.f, 0.f, 0.f};
    accb(acc, g2b[(size_t)node * 4 + l4]);             // self term

    for (int k0 = 0; k0 < c; k0 += 4) {
        int k = k0 + l4;
        int sidx = (k < c) ? csr_src[b + k] : 0;
        int nj = min(4, c - k0);
        if (nj == 4) {
            int s0 = __shfl(sidx, g0 + 0);
            int s1 = __shfl(sidx, g0 + 1);
            int s2 = __shfl(sidx, g0 + 2);
            int s3 = __shfl(sidx, g0 + 3);
            uint2 u0 = g2b[(size_t)s0 * 4 + l4];       // 4 independent 32B rows
            uint2 u1 = g2b[(size_t)s1 * 4 + l4];
            uint2 u2 = g2b[(size_t)s2 * 4 + l4];
            uint2 u3 = g2b[(size_t)s3 * 4 + l4];
            accb(acc, u0); accb(acc, u1); accb(acc, u2); accb(acc, u3);
        } else {
            for (int j = 0; j < nj; ++j)
                accb(acc, g2b[(size_t)__shfl(sidx, g0 + j) * 4 + l4]);
        }
    }
    float4 bv = ((const float4*)b2)[l4];
    float4 r  = { fmaf(di, acc.x, bv.x), fmaf(di, acc.y, bv.y),
                  fmaf(di, acc.z, bv.z), fmaf(di, acc.w, bv.w) };
    ((float4*)out)[(size_t)node * 4 + l4] = r;
}

extern "C" void kernel_launch(void* const* d_in, const int* in_sizes, int n_in,
                              void* d_out, int out_size, void* d_ws, size_t ws_size,
                              hipStream_t stream) {
    const float* x     = (const float*)d_in[0];
    const int*   edges = (const int*)d_in[1];              // int32 (harness converts)
    const float* W1    = (const float*)d_in[2];
    const float* b1    = (const float*)d_in[3];
    const float* W2    = (const float*)d_in[4];
    const float* b2    = (const float*)d_in[5];
    float*       out   = (float*)d_out;

    const int E = in_sizes[1] / 2;                         // 3,200,000

    // workspace (~32.8 MB), concurrently-live regions disjoint:
    //   [0, 14.0 MB):    pairs (build)  -> g1b (bf16 12.8 MB; live through gather1)
    //   [14.0, 17.2 MB): g2b (bf16, N*4 uint2 = 3.2 MB; written by gather1)
    //   [17.2, 31.2 MB): csr_src (NBKT*CAP ints)
    //   [31.2, ...):     nbase | ncnt | dinv | bkt_tail
    int*   pairs   = (int*)d_ws;                           // NBKT*CAP ints
    uint2* g1b     = (uint2*)d_ws;                         // N*16 uint2 (bf16 rows)
    uint2* g2b     = (uint2*)((float*)d_ws + (size_t)NBKT * CAP);
    int*   csr_src = (int*)g2b + (size_t)N_NODES * 8 + 64; // AFTER g2b (R9 bug: was N*2)
    int*   nbase   = csr_src + (size_t)NBKT * CAP;         // N
    int*   ncnt    = nbase + N_NODES;                      // N
    float* dinv    = (float*)(ncnt + N_NODES);             // N
    int*   bkt_tail= (int*)(dinv + N_NODES);               // NBKT*16

    const int nchunk = (E + CHUNK - 1) / CHUNK;            // 782

    // CSR build (single-pass padded-bucket sort by dst)
    k_zero_b <<<(NBKT * BKT_PAD + 255) / 256, 256, 0, stream>>>(bkt_tail);
    k_bfill  <<<nchunk, 256, 0, stream>>>((const int2*)edges, bkt_tail, pairs, E);
    k_bnode  <<<NBKT, 256, 0, stream>>>(pairs, bkt_tail, csr_src, nbase, ncnt, dinv);

    // layer 1 GEMM (dinv-prescaled bf16 rows)
    k_gemm1   <<<N_NODES / 16, 256, 0, stream>>>(x, W1, dinv, g1b);

    // fused: gather1 + bias + relu + GEMM2 (+dinv prescale) -> g2b
    k_gather1 <<<6250, 256, 0, stream>>>(csr_src, nbase, ncnt, dinv, g1b, b1, W2, g2b);

    // gather layer 2 -> out
    k_gather2 <<<1563, 256, 0, stream>>>(csr_src, nbase, ncnt, dinv, g2b, b2, out);
}